// Round 4
// baseline (582.796 us; speedup 1.0000x reference)
//
#include <hip/hip_runtime.h>

// PWC-Net 9x9 correlation — r4: CB=4 multi-channel staging, 3-wave blocks.
//
// r3 post-mortem: conflicts fixed (9.3M->1.0M) but 229us. Budget: FMA floor
// 23us, LDS pipe ~56us, measured 4294 cyc/channel -> ~75% of time was the
// per-channel __syncthreads vmcnt(0) drain (1 barrier per channel, only
// 72 cyc of FMA per wave to hide it, 6-wave barriers).
// r4 stages 4 channels per LDS buffer (double-buffered, 24KB), so one
// barrier covers 12 ds_read + 144 FMA per wave, and the prefetch issued at
// iteration start has the whole compute phase to complete. Blocks shrink to
// 3 waves (YT=4, grid=2016) for cheaper barriers and ~6-8 independent
// blocks/CU of latency hiding. Layout stays the conflict-free PX=4 mapping
// (every ds_read_b128 lane-contiguous); F stays in registers (coalesced
// float4 loads, prefetched one buffer ahead).
//
// OOB handling unchanged:
//  - second rows outside [0,H): per-lane staging source -> zeroed
//    __device__ row, stride 0 (covers all CB channels).
//  - x window halo: thread-constant LDS pointer -> 16B zero pad, stride 0.
//
// Numerics: same channel-sequential fmaf chain, same 1/C scale.

namespace {
constexpr int kC = 128;
constexpr int kH = 112;
constexpr int kW = 192;
constexpr int kD = 4;            // max displacement
constexpr int kKD = 9;           // 2*kD+1
constexpr int kHW = kH * kW;     // 21504
constexpr long long kCHW = (long long)kC * kHW;

constexpr int PX = 4;            // pixels per thread along x
constexpr int XG = kW / PX;      // 48 lanes cover one row, contiguous 16B each
constexpr int YT = 4;            // rows per block
constexpr int NT = XG * YT;      // 192 threads = 3 waves
constexpr int TILE = YT * kW;    // 768 floats per staged channel tile
constexpr int CB = 4;            // channels staged per buffer
}  // namespace

// 768B of zeros: staging source for out-of-image second rows.
__device__ __attribute__((aligned(16))) float g_zero_row[kW] = {};

typedef const __attribute__((address_space(1))) void* gas_ptr;
typedef __attribute__((address_space(3))) void* las_ptr;

__device__ __forceinline__ void gload16(const float* g, float* l) {
  __builtin_amdgcn_global_load_lds((gas_ptr)g, (las_ptr)l, 16, 0, 0);
}

__global__ __launch_bounds__(NT, 4)
void corr81_kernel(const float* __restrict__ first,
                   const float* __restrict__ second,
                   float* __restrict__ out) {
  __shared__ __align__(16) float zpad[4];          // x-halo zeros
  __shared__ __align__(16) float Sb[2][CB][TILE];  // 2 x 4 x 3KB = 24KB

  const int g = blockIdx.x;
  const int b = g & 7;             // batch -> XCD slab
  const int i = g >> 3;
  const int dy = i % kKD;          // dy innermost -> L2 sliding window
  const int y0 = (i / kKD) * YT;

  const int tid = threadIdx.x;
  const int xg = tid % XG;         // lane's x-group (contiguous 16B per lane)
  const int yl = tid / XG;         // lane's row in tile (0..3)
  const int px0 = xg * PX;
  const int ys0 = y0 + dy - kD + yl;  // this lane's staged second-row

  if (tid == 0) { zpad[0] = 0.f; zpad[1] = 0.f; zpad[2] = 0.f; zpad[3] = 0.f; }

  // ---- S staging source (per lane, one 16B per channel). tid*4 in the tile
  // equals yl*kW + px0, so staging and consumption use the same mapping.
  const bool inb = (unsigned)ys0 < (unsigned)kH;
  const float* ssrc = inb
      ? (second + (long long)b * kCHW + (long long)ys0 * kW + px0)
      : (g_zero_row + px0);
  const long long sstr = inb ? (long long)kHW : 0ll;

  // ---- F source: lane's own 4 pixels, coalesced float4, register prefetch.
  const float* fp = first + (long long)b * kCHW + (long long)(y0 + yl) * kW + px0;

  float acc[PX][kKD];
#pragma unroll
  for (int p = 0; p < PX; ++p)
#pragma unroll
    for (int d = 0; d < kKD; ++d) acc[p][d] = 0.0f;

  // thread-constant compute pointers (per buffer); per-channel advance is a
  // compile-time stride (0 for the zpad halo so it never walks off the pad).
  const float* s1b[2] = {&Sb[0][0][yl * kW + px0], &Sb[1][0][yl * kW + px0]};
  const float* w0b[2] = {(xg == 0) ? zpad : s1b[0] - PX,
                         (xg == 0) ? zpad : s1b[1] - PX};
  const float* w2b[2] = {(xg == XG - 1) ? zpad : s1b[0] + PX,
                         (xg == XG - 1) ? zpad : s1b[1] + PX};
  const int wstr0 = (xg == 0) ? 0 : TILE;
  const int wstr2 = (xg == XG - 1) ? 0 : TILE;

  // issue CB gload16 (one per channel) into buffer P, advance source
  auto stage = [&](int P) {
#pragma unroll
    for (int k = 0; k < CB; ++k)
      gload16(ssrc + (long long)k * sstr, &Sb[P][k][tid * PX]);
    ssrc += (long long)CB * sstr;
  };

  // load CB channels of F into registers, advance source
  auto loadF = [&](float4* f) {
#pragma unroll
    for (int k = 0; k < CB; ++k)
      f[k] = *(const float4*)(fp + (long long)k * kHW);
    fp += (long long)CB * kHW;
  };

  // CB channels of compute from buffer P: per channel 3 ds_read_b128 + 36 FMA
  auto compute = [&](int P, const float4* f) {
    const float* s1p = s1b[P];
    const float* w0p = w0b[P];
    const float* w2p = w2b[P];
#pragma unroll
    for (int k = 0; k < CB; ++k) {
      const float4 w0 = *(const float4*)(w0p);  // floats [px0-4, px0)
      const float4 w1 = *(const float4*)(s1p);  // floats [px0, px0+4)
      const float4 w2 = *(const float4*)(w2p);  // floats [px0+4, px0+8)
      const float fa[PX] = {f[k].x, f[k].y, f[k].z, f[k].w};
      const float sw[12] = {w0.x, w0.y, w0.z, w0.w, w1.x, w1.y, w1.z, w1.w,
                            w2.x, w2.y, w2.z, w2.w};
#pragma unroll
      for (int p = 0; p < PX; ++p)
#pragma unroll
        for (int d = 0; d < kKD; ++d)
          acc[p][d] = fmaf(fa[p], sw[p + d], acc[p][d]);
      s1p += TILE;
      w0p += wstr0;
      w2p += wstr2;
    }
  };

  // ---- software-pipelined channel loop: 8 channels per iteration ----
  float4 fcur[CB], fnext[CB];
  stage(0);                      // S channels 0..3
  loadF(fcur);                   // F channels 0..3
  __syncthreads();               // buf0 + zpad ready
  for (int c = 0; c < kC; c += 2 * CB) {
    stage(1);                    // S channels c+4..c+7
    loadF(fnext);                // F channels c+4..c+7
    compute(0, fcur);            // channels c..c+3
    __syncthreads();             // buf1 ready; buf0 consumed
    if (c + 2 * CB < kC) {
      stage(0);                  // S channels c+8..c+11
      loadF(fcur);               // F channels c+8..c+11
    }
    compute(1, fnext);           // channels c+4..c+7
    __syncthreads();             // buf0 ready; buf1 consumed
  }

  // epilogue: 9 dx channels x 4 px, coalesced dwordx4 stores
  const float scale = 1.0f / (float)kC;
  float* obase = out + ((long long)b * 81 + (long long)dy * kKD) * kHW +
                 (long long)(y0 + yl) * kW + px0;
#pragma unroll
  for (int d = 0; d < kKD; ++d) {
    float4 o = make_float4(acc[0][d] * scale, acc[1][d] * scale,
                           acc[2][d] * scale, acc[3][d] * scale);
    *(float4*)(obase + (long long)d * kHW) = o;
  }
}

extern "C" void kernel_launch(void* const* d_in, const int* in_sizes, int n_in,
                              void* d_out, int out_size, void* d_ws, size_t ws_size,
                              hipStream_t stream) {
  const float* first = (const float*)d_in[0];
  const float* second = (const float*)d_in[1];
  float* out = (float*)d_out;

  const int grid = 8 * (kH / YT) * kKD;  // 8 * 28 * 9 = 2016 blocks
  corr81_kernel<<<grid, NT, 0, stream>>>(first, second, out);
}

// Round 5
// 582.324 us; speedup vs baseline: 1.0008x; 1.0008x over previous
//
#include <hip/hip_runtime.h>

// PWC-Net 9x9 correlation — r5: CB=4 staging with spill-free register F.
//
// r4 post-mortem: 458us, FETCH 438MB / WRITE 698MB (vs 86/54 ideal). The
// loadF(float4*)/compute(const float4*) lambda-pointer plumbing made
// fcur[]/fnext[] address-taken -> compiler kept them in scratch -> every
// channel group did a scratch round-trip (644MB of extra HBM writes).
// The CB=4 barrier-amortization schedule itself was never measured.
// r5 = same schedule, but all pipeline state in named scalar float4s moved
// by macros; per-buffer LDS base pointers are named scalars chosen at
// compile time. No address-taken arrays, no runtime-indexed locals.
//
// Schedule (from r4 theory): stage 4 channels per LDS buffer (2x4x3KB=24KB),
// one __syncthreads per 4 channels (33 barriers total, not 129), ~144 FMA +
// 12 ds_read per wave between barriers so the prefetch issued at iteration
// start completes before the drain. 3-wave blocks (YT=4, grid 2016).
// Layout stays the conflict-free PX=4 mapping (every ds_read_b128
// lane-contiguous; 48 lanes cover one 192-float row).
//
// OOB handling:
//  - second rows outside [0,H): per-lane staging source -> zeroed
//    __device__ row, stride 0 (covers all CB channels).
//  - x window halo: thread-constant LDS pointer -> 16B zero pad, stride 0.
//
// Numerics: same channel-sequential fmaf chain, same 1/C scale.

namespace {
constexpr int kC = 128;
constexpr int kH = 112;
constexpr int kW = 192;
constexpr int kD = 4;            // max displacement
constexpr int kKD = 9;           // 2*kD+1
constexpr int kHW = kH * kW;     // 21504
constexpr long long kCHW = (long long)kC * kHW;

constexpr int PX = 4;            // pixels per thread along x
constexpr int XG = kW / PX;      // 48 lanes cover one row, contiguous 16B each
constexpr int YT = 4;            // rows per block
constexpr int NT = XG * YT;      // 192 threads = 3 waves
constexpr int TILE = YT * kW;    // 768 floats per staged channel tile
constexpr int CB = 4;            // channels staged per buffer
}  // namespace

// 768B of zeros: staging source for out-of-image second rows.
__device__ __attribute__((aligned(16))) float g_zero_row[kW] = {};

typedef const __attribute__((address_space(1))) void* gas_ptr;
typedef __attribute__((address_space(3))) void* las_ptr;

__device__ __forceinline__ void gload16(const float* g, float* l) {
  __builtin_amdgcn_global_load_lds((gas_ptr)g, (las_ptr)l, 16, 0, 0);
}

__global__ __launch_bounds__(NT, 4)
void corr81_kernel(const float* __restrict__ first,
                   const float* __restrict__ second,
                   float* __restrict__ out) {
  __shared__ __align__(16) float zpad[4];          // x-halo zeros
  __shared__ __align__(16) float Sb[2][CB][TILE];  // 2 x 4 x 3KB = 24KB

  const int g = blockIdx.x;
  const int b = g & 7;             // batch -> XCD slab
  const int i = g >> 3;
  const int dy = i % kKD;          // dy innermost -> L2 sliding window
  const int y0 = (i / kKD) * YT;

  const int tid = threadIdx.x;
  const int xg = tid % XG;         // lane's x-group (contiguous 16B per lane)
  const int yl = tid / XG;         // lane's row in tile (0..3)
  const int px0 = xg * PX;
  const int ys0 = y0 + dy - kD + yl;  // this lane's staged second-row

  if (tid == 0) { zpad[0] = 0.f; zpad[1] = 0.f; zpad[2] = 0.f; zpad[3] = 0.f; }

  // ---- S staging source (per lane, one 16B per channel). tid*4 in the tile
  // equals yl*kW + px0, so staging and consumption use the same mapping.
  const bool inb = (unsigned)ys0 < (unsigned)kH;
  const float* ssrc = inb
      ? (second + (long long)b * kCHW + (long long)ys0 * kW + px0)
      : (g_zero_row + px0);
  const long long sstr = inb ? (long long)kHW : 0ll;

  // ---- F source: lane's own 4 pixels, coalesced float4, register prefetch.
  const float* fp = first + (long long)b * kCHW + (long long)(y0 + yl) * kW + px0;

  float acc[PX][kKD];
#pragma unroll
  for (int p = 0; p < PX; ++p)
#pragma unroll
    for (int d = 0; d < kKD; ++d) acc[p][d] = 0.0f;

  // thread-constant per-buffer base pointers — named scalars, no arrays.
  const float* s1b0 = &Sb[0][0][yl * kW + px0];
  const float* s1b1 = &Sb[1][0][yl * kW + px0];
  const float* w0b0 = (xg == 0) ? zpad : s1b0 - PX;
  const float* w0b1 = (xg == 0) ? zpad : s1b1 - PX;
  const float* w2b0 = (xg == XG - 1) ? zpad : s1b0 + PX;
  const float* w2b1 = (xg == XG - 1) ? zpad : s1b1 + PX;
  const int wstr0 = (xg == 0) ? 0 : TILE;        // zpad never advances
  const int wstr2 = (xg == XG - 1) ? 0 : TILE;

#define STAGE(P)                                          \
  do {                                                    \
    gload16(ssrc,            &Sb[P][0][tid * PX]);        \
    gload16(ssrc + sstr,     &Sb[P][1][tid * PX]);        \
    gload16(ssrc + 2 * sstr, &Sb[P][2][tid * PX]);        \
    gload16(ssrc + 3 * sstr, &Sb[P][3][tid * PX]);        \
    ssrc += 4 * sstr;                                     \
  } while (0)

#define LOADF(F0, F1, F2, F3)                             \
  do {                                                    \
    F0 = *(const float4*)(fp);                            \
    F1 = *(const float4*)(fp + kHW);                      \
    F2 = *(const float4*)(fp + 2 * kHW);                  \
    F3 = *(const float4*)(fp + 3 * kHW);                  \
    fp += 4LL * kHW;                                      \
  } while (0)

  // one channel: 3 lane-contiguous ds_read_b128 + 36 FMA
#define CH(S1, W0P, W2P, F)                                                  \
  do {                                                                       \
    const float4 W0 = *(const float4*)(W0P);  /* floats [px0-4, px0)  */     \
    const float4 W1 = *(const float4*)(S1);   /* floats [px0,  px0+4) */     \
    const float4 W2 = *(const float4*)(W2P);  /* floats [px0+4,px0+8) */     \
    const float sw[12] = {W0.x, W0.y, W0.z, W0.w, W1.x, W1.y, W1.z, W1.w,    \
                          W2.x, W2.y, W2.z, W2.w};                           \
    const float fv[PX] = {F.x, F.y, F.z, F.w};                               \
    _Pragma("unroll") for (int p = 0; p < PX; ++p)                           \
        _Pragma("unroll") for (int d = 0; d < kKD; ++d)                      \
            acc[p][d] = fmaf(fv[p], sw[p + d], acc[p][d]);                   \
  } while (0)

#define COMPUTE(S1B, W0B, W2B, F0, F1, F2, F3)            \
  do {                                                    \
    const float* s1_ = S1B;                               \
    const float* w0_ = W0B;                               \
    const float* w2_ = W2B;                               \
    CH(s1_, w0_, w2_, F0);                                \
    s1_ += TILE; w0_ += wstr0; w2_ += wstr2;              \
    CH(s1_, w0_, w2_, F1);                                \
    s1_ += TILE; w0_ += wstr0; w2_ += wstr2;              \
    CH(s1_, w0_, w2_, F2);                                \
    s1_ += TILE; w0_ += wstr0; w2_ += wstr2;              \
    CH(s1_, w0_, w2_, F3);                                \
  } while (0)

  // ---- software-pipelined channel loop: 8 channels per iteration ----
  float4 fa0, fa1, fa2, fa3, fb0, fb1, fb2, fb3;
  STAGE(0);                          // S channels 0..3
  LOADF(fa0, fa1, fa2, fa3);         // F channels 0..3
  __syncthreads();                   // buf0 + zpad ready
  for (int c = 0; c < kC; c += 2 * CB) {
    STAGE(1);                        // S channels c+4..c+7
    LOADF(fb0, fb1, fb2, fb3);       // F channels c+4..c+7
    COMPUTE(s1b0, w0b0, w2b0, fa0, fa1, fa2, fa3);   // channels c..c+3
    __syncthreads();                 // buf1 ready; buf0 consumed
    if (c + 2 * CB < kC) {
      STAGE(0);                      // S channels c+8..c+11
      LOADF(fa0, fa1, fa2, fa3);     // F channels c+8..c+11
    }
    COMPUTE(s1b1, w0b1, w2b1, fb0, fb1, fb2, fb3);   // channels c+4..c+7
    __syncthreads();                 // buf0 ready; buf1 consumed
  }

#undef STAGE
#undef LOADF
#undef CH
#undef COMPUTE

  // epilogue: 9 dx channels x 4 px, coalesced dwordx4 stores
  const float scale = 1.0f / (float)kC;
  float* obase = out + ((long long)b * 81 + (long long)dy * kKD) * kHW +
                 (long long)(y0 + yl) * kW + px0;
#pragma unroll
  for (int d = 0; d < kKD; ++d) {
    float4 o = make_float4(acc[0][d] * scale, acc[1][d] * scale,
                           acc[2][d] * scale, acc[3][d] * scale);
    *(float4*)(obase + (long long)d * kHW) = o;
  }
}

extern "C" void kernel_launch(void* const* d_in, const int* in_sizes, int n_in,
                              void* d_out, int out_size, void* d_ws, size_t ws_size,
                              hipStream_t stream) {
  const float* first = (const float*)d_in[0];
  const float* second = (const float*)d_in[1];
  float* out = (float*)d_out;

  const int grid = 8 * (kH / YT) * kKD;  // 8 * 28 * 9 = 2016 blocks
  corr81_kernel<<<grid, NT, 0, stream>>>(first, second, out);
}

// Round 6
// 449.623 us; speedup vs baseline: 1.2962x; 1.2951x over previous
//
#include <hip/hip_runtime.h>

// PWC-Net 9x9 correlation — r6: r2 geometry + conflict-free split-pixel
// layout + register F. (r4/r5's CB=4 schedule produced unexplained ~1GB/
// dispatch scratch-like traffic in two variants; reverted to proven base.)
//
// Structure (all elements individually measured clean):
//  - YT=8 rows, NT=192 (3 waves), grid 1008, b=g&7 XCD slab, dy innermost
//    [r2: 153us, FETCH 86MB, WRITE 54MB]
//  - per-channel double-buffered S tile in LDS via global_load_lds,
//    one __syncthreads per channel [r2-proven schedule]
//  - split-pixel mapping: 24 lanes/row, lane owns px [4xg,4xg+4) and
//    [96+4xg,96+4xg+4). All ds_read_b128 at 16B lane stride -> 8 words/bank
//    /wave, zero conflicts by construction [r3-proven layout arithmetic]
//  - F in registers: 2 coalesced float4 global loads per channel, double-
//    buffered in named scalars [r3-proven clean codegen]
//
// OOB: second rows outside [0,H) -> staging source = zeroed __device__ row,
// stride 0. x-halo (first-half left @xg==0, second-half right @xg==23) ->
// thread-constant pointer to 16B LDS zero pad.
//
// Numerics: channel-sequential fmaf chain, 1/C scale (absmax 2e-3 baseline).

namespace {
constexpr int kC = 128;
constexpr int kH = 112;
constexpr int kW = 192;
constexpr int kD = 4;             // max displacement
constexpr int kKD = 9;            // 2*kD+1
constexpr int kHW = kH * kW;      // 21504
constexpr long long kCHW = (long long)kC * kHW;

constexpr int HPX = 4;            // pixels per half-group
constexpr int XG = 24;            // lanes per row
constexpr int YT = 8;             // rows per block
constexpr int NT = XG * YT;       // 192 threads = 3 waves
constexpr int TILE = YT * kW;     // 1536 floats = 6KB per S tile
}  // namespace

// 768B of zeros: staging source for out-of-image second rows.
__device__ __attribute__((aligned(16))) float g_zero_row[kW] = {};

typedef const __attribute__((address_space(1))) void* gas_ptr;
typedef __attribute__((address_space(3))) void* las_ptr;

__device__ __forceinline__ void gload16(const float* g, float* l) {
  __builtin_amdgcn_global_load_lds((gas_ptr)g, (las_ptr)l, 16, 0, 0);
}

__global__ __launch_bounds__(NT, 4)
void corr81_kernel(const float* __restrict__ first,
                   const float* __restrict__ second,
                   float* __restrict__ out) {
  __shared__ __align__(16) float zpad[4];      // x-halo zeros
  __shared__ __align__(16) float Sb[2][TILE];  // second tiles (double buffer)

  const int g = blockIdx.x;
  const int b = g & 7;             // batch -> XCD slab
  const int i = g >> 3;
  const int dy = i % kKD;          // dy innermost -> L2 sliding window
  const int y0 = (i / kKD) * YT;

  const int tid = threadIdx.x;
  const int xg = tid % XG;         // lane's x-group within its row
  const int yl = tid / XG;         // lane's row in tile (0..7)
  const int px0 = xg * HPX;        // first-half pixel base; second = 96+px0

  if (tid == 0) { zpad[0] = 0.f; zpad[1] = 0.f; zpad[2] = 0.f; zpad[3] = 0.f; }

  // ---- S staging sources: slots tid and tid+NT; slot s -> row s/48,
  // col (s%48)*4; LDS byte s*16 (linear). OOB rows -> zero row, stride 0.
  const float* ssrcA;
  const float* ssrcB;
  long long sstrA, sstrB;
  {
    const int sA = tid;
    const int rA = sA / 48, cA = (sA % 48) * 4;
    const int yA = y0 + dy - kD + rA;
    const bool inbA = (unsigned)yA < (unsigned)kH;
    ssrcA = inbA ? (second + (long long)b * kCHW + (long long)yA * kW + cA)
                 : (g_zero_row + cA);
    sstrA = inbA ? (long long)kHW : 0ll;

    const int sB = tid + NT;
    const int rB = sB / 48, cB = (sB % 48) * 4;
    const int yB = y0 + dy - kD + rB;
    const bool inbB = (unsigned)yB < (unsigned)kH;
    ssrcB = inbB ? (second + (long long)b * kCHW + (long long)yB * kW + cB)
                 : (g_zero_row + cB);
    sstrB = inbB ? (long long)kHW : 0ll;
  }

  // ---- F source: lane's own row; two float4s per channel (px0 and 96+px0).
  const float* fp = first + (long long)b * kCHW + (long long)(y0 + yl) * kW;

  // ---- accumulators: two half-groups x 4 px x 9 dx = 72 VGPR
  float acc0[HPX][kKD];
  float acc1[HPX][kKD];
#pragma unroll
  for (int p = 0; p < HPX; ++p)
#pragma unroll
    for (int d = 0; d < kKD; ++d) { acc0[p][d] = 0.0f; acc1[p][d] = 0.0f; }

  // ---- thread-constant window pointers, fixed per buffer (no walking).
  // Half 0 window floats: [px0-4,px0) [px0,px0+4) [px0+4,px0+8)
  // Half 1 window floats: [92+px0,96+px0) [96+px0,100+px0) [100+px0,104+px0)
  const int rb = yl * kW;
  const float* a0_0 = (xg == 0) ? zpad : &Sb[0][rb + px0 - 4];
  const float* a1_0 = &Sb[0][rb + px0];
  const float* a2_0 = &Sb[0][rb + px0 + 4];
  const float* b0_0 = &Sb[0][rb + 92 + px0];
  const float* b1_0 = &Sb[0][rb + 96 + px0];
  const float* b2_0 = (xg == XG - 1) ? zpad : &Sb[0][rb + 100 + px0];
  const float* a0_1 = (xg == 0) ? zpad : &Sb[1][rb + px0 - 4];
  const float* a1_1 = &Sb[1][rb + px0];
  const float* a2_1 = &Sb[1][rb + px0 + 4];
  const float* b0_1 = &Sb[1][rb + 92 + px0];
  const float* b1_1 = &Sb[1][rb + 96 + px0];
  const float* b2_1 = (xg == XG - 1) ? zpad : &Sb[1][rb + 100 + px0];

  // one channel of FMAs: 6 lane-contiguous ds_read_b128 + 72 FMA
  auto computeCh = [&](const float* w0p, const float* w1p, const float* w2p,
                       const float* v0p, const float* v1p, const float* v2p,
                       const float4 fA, const float4 fB) {
    {
      const float4 w0 = *(const float4*)(w0p);
      const float4 w1 = *(const float4*)(w1p);
      const float4 w2 = *(const float4*)(w2p);
      const float sw[12] = {w0.x, w0.y, w0.z, w0.w, w1.x, w1.y, w1.z, w1.w,
                            w2.x, w2.y, w2.z, w2.w};
      const float fv[HPX] = {fA.x, fA.y, fA.z, fA.w};
#pragma unroll
      for (int p = 0; p < HPX; ++p)
#pragma unroll
        for (int d = 0; d < kKD; ++d)
          acc0[p][d] = fmaf(fv[p], sw[p + d], acc0[p][d]);
    }
    {
      const float4 w0 = *(const float4*)(v0p);
      const float4 w1 = *(const float4*)(v1p);
      const float4 w2 = *(const float4*)(v2p);
      const float sw[12] = {w0.x, w0.y, w0.z, w0.w, w1.x, w1.y, w1.z, w1.w,
                            w2.x, w2.y, w2.z, w2.w};
      const float fv[HPX] = {fB.x, fB.y, fB.z, fB.w};
#pragma unroll
      for (int p = 0; p < HPX; ++p)
#pragma unroll
        for (int d = 0; d < kKD; ++d)
          acc1[p][d] = fmaf(fv[p], sw[p + d], acc1[p][d]);
    }
  };

  // stage one channel's S tile (6KB) into buffer P: 2 gload16 per lane
  auto stage0 = [&]() {
    gload16(ssrcA, &Sb[0][tid * 4]);
    gload16(ssrcB, &Sb[0][(tid + NT) * 4]);
    ssrcA += sstrA;
    ssrcB += sstrB;
  };
  auto stage1 = [&]() {
    gload16(ssrcA, &Sb[1][tid * 4]);
    gload16(ssrcB, &Sb[1][(tid + NT) * 4]);
    ssrcA += sstrA;
    ssrcB += sstrB;
  };

  // ---- per-channel double-buffered loop (r2 schedule, unroll 2) ----
  float4 faL, faH, fbL, fbH;
  stage0();                                     // S for c=0
  faL = *(const float4*)(fp + px0);             // F for c=0
  faH = *(const float4*)(fp + 96 + px0);
  fp += kHW;
  __syncthreads();                              // buf0 + zpad ready
  for (int c = 0; c < kC; c += 2) {
    stage1();                                   // S for c+1
    fbL = *(const float4*)(fp + px0);           // F for c+1
    fbH = *(const float4*)(fp + 96 + px0);
    fp += kHW;
    computeCh(a0_0, a1_0, a2_0, b0_0, b1_0, b2_0, faL, faH);  // channel c
    __syncthreads();                            // buf1 ready; buf0 consumed
    if (c + 2 < kC) {
      stage0();                                 // S for c+2
      faL = *(const float4*)(fp + px0);         // F for c+2
      faH = *(const float4*)(fp + 96 + px0);
      fp += kHW;
    }
    computeCh(a0_1, a1_1, a2_1, b0_1, b1_1, b2_1, fbL, fbH);  // channel c+1
    __syncthreads();                            // buf0 ready; buf1 consumed
  }

  // epilogue: 9 dx channels x (2 x 4 px), coalesced dwordx4 stores
  const float scale = 1.0f / (float)kC;
  float* obase = out + ((long long)b * 81 + (long long)dy * kKD) * kHW +
                 (long long)(y0 + yl) * kW;
#pragma unroll
  for (int d = 0; d < kKD; ++d) {
    float4 o0 = make_float4(acc0[0][d] * scale, acc0[1][d] * scale,
                            acc0[2][d] * scale, acc0[3][d] * scale);
    float4 o1 = make_float4(acc1[0][d] * scale, acc1[1][d] * scale,
                            acc1[2][d] * scale, acc1[3][d] * scale);
    float* op = obase + (long long)d * kHW;
    *(float4*)(op + px0) = o0;
    *(float4*)(op + 96 + px0) = o1;
  }
}

extern "C" void kernel_launch(void* const* d_in, const int* in_sizes, int n_in,
                              void* d_out, int out_size, void* d_ws, size_t ws_size,
                              hipStream_t stream) {
  const float* first = (const float*)d_in[0];
  const float* second = (const float*)d_in[1];
  float* out = (float*)d_out;

  const int grid = 8 * (kH / YT) * kKD;  // 8 * 14 * 9 = 1008 blocks
  corr81_kernel<<<grid, NT, 0, stream>>>(first, second, out);
}

// Round 7
// 378.292 us; speedup vs baseline: 1.5406x; 1.1886x over previous
//
#include <hip/hip_runtime.h>

// PWC-Net 9x9 correlation — r7: r2 VERBATIM body + triple-buffer with
// counted vmcnt(4) + raw s_barrier (T4: never drain vmcnt in the loop).
//
// r2 (153us, best measured): per-channel __syncthreads drains the stage
// issued only one phase earlier -> 300-900cy latency exposed per channel
// (~45% of runtime). r4/r5/r6 restructures all hit a codegen pathology
// (acc pushed out of AGPRs -> scratch, WRITE_SIZE 273-698MB), so this
// round changes ONLY the synchronization:
//   period-3 loop, phase = { compute(bX); s_waitcnt vmcnt(4); s_barrier;
//   stage(bX -> c+3) }. Steady state: 8 loads outstanding; each vmcnt(4)
//   retires exactly the 4 loads staged TWO compute phases ago; the barrier
//   after the wait publishes buffer validity to all waves (m201 pattern,
//   race-free). One full __syncthreads in the prologue only.
//
// Everything else (geometry, stage/compute bodies, OOB handling, epilogue,
// numerics) is byte-identical to the verified r2 kernel.

namespace {
constexpr int kC = 128;
constexpr int kH = 112;
constexpr int kW = 192;
constexpr int kD = 4;            // max displacement
constexpr int kKD = 9;           // 2*kD+1
constexpr int kHW = kH * kW;     // 21504
constexpr long long kCHW = (long long)kC * kHW;

constexpr int PX = 8;            // pixels per thread along x
constexpr int XG = kW / PX;      // 24 x-groups
constexpr int YT = 8;            // rows per block
constexpr int NT = XG * YT;      // 192 threads = 3 waves
constexpr int TILE = YT * kW;    // 1536 floats per staged channel tile
}  // namespace

// 768B of zeros: staging source for out-of-image second rows.
__device__ __attribute__((aligned(16))) float g_zero_row[kW] = {};

typedef const __attribute__((address_space(1))) void* gas_ptr;
typedef __attribute__((address_space(3))) void* las_ptr;

__device__ __forceinline__ void gload16(const float* g, float* l) {
  __builtin_amdgcn_global_load_lds((gas_ptr)g, (las_ptr)l, 16, 0, 0);
}

__global__ __launch_bounds__(NT, 4)
void corr81_kernel(const float* __restrict__ first,
                   const float* __restrict__ second,
                   float* __restrict__ out) {
  __shared__ __align__(16) float zpad[4];        // x-halo zeros
  __shared__ __align__(16) float Sb[3][TILE];    // second tiles (triple buffer)
  __shared__ __align__(16) float Fb[3][TILE];    // first tiles  (triple buffer)

  const int g = blockIdx.x;
  const int b = g & 7;             // batch -> XCD slab
  const int i = g >> 3;
  const int dy = i % kKD;          // dy innermost -> L2 sliding window
  const int y0 = (i / kKD) * YT;

  const int tid = threadIdx.x;
  const int xg = tid % XG;
  const int yl = tid / XG;
  const int px0 = xg * PX;
  const int ys0 = y0 + dy - kD;    // first staged second-row (may be OOB)

  if (tid == 0) { zpad[0] = 0.f; zpad[1] = 0.f; zpad[2] = 0.f; zpad[3] = 0.f; }

  // ---- staging source pointers (per lane, computed once; r2 verbatim) ----
  const float* fsrc = first + (long long)b * kCHW + (long long)y0 * kW +
                      (long long)tid * 4;
  const float* ssrc[2];
  long long sstr[2];
#pragma unroll
  for (int j = 0; j < 2; ++j) {
    const int pos = j * NT + tid;          // 0..383
    const int r = pos / 48;                // staged row 0..7
    const int col4 = (pos - r * 48) * 4;   // float offset within row
    const int ysr = ys0 + r;
    const bool inb = (unsigned)ysr < (unsigned)kH;
    ssrc[j] = inb ? (second + (long long)b * kCHW + (long long)ysr * kW + col4)
                  : (g_zero_row + col4);
    sstr[j] = inb ? (long long)kHW : 0ll;
  }

  float acc[PX][kKD];
#pragma unroll
  for (int p = 0; p < PX; ++p)
#pragma unroll
    for (int d = 0; d < kKD; ++d) acc[p][d] = 0.0f;

  // issue 4 x global_load_lds (12KB) for one channel into buffer P, advance
  auto stage = [&](int P) {
    gload16(fsrc,            &Fb[P][tid * 4]);
    gload16(fsrc + NT * 4,   &Fb[P][tid * 4 + NT * 4]);
    gload16(ssrc[0],         &Sb[P][tid * 4]);
    gload16(ssrc[1],         &Sb[P][tid * 4 + NT * 4]);
    fsrc += kHW;
    ssrc[0] += sstr[0];
    ssrc[1] += sstr[1];
  };

  // 6 x ds_read_b128 + 72 FMA from buffer P (r2 verbatim)
  auto compute = [&](int P) {
    const float* fp = &Fb[P][yl * kW + px0];
    const float* s1 = &Sb[P][yl * kW + px0];
    const float* w0p = (xg == 0) ? zpad : (s1 - 4);       // window [-4,0)
    const float* w3p = (xg == XG - 1) ? zpad : (s1 + 8);  // window [12,16)
    const float4 f0 = *(const float4*)(fp);
    const float4 f1 = *(const float4*)(fp + 4);
    const float4 w0 = *(const float4*)(w0p);
    const float4 w1 = *(const float4*)(s1);
    const float4 w2 = *(const float4*)(s1 + 4);
    const float4 w3 = *(const float4*)(w3p);

    const float fa[PX] = {f0.x, f0.y, f0.z, f0.w, f1.x, f1.y, f1.z, f1.w};
    const float sw[16] = {w0.x, w0.y, w0.z, w0.w, w1.x, w1.y, w1.z, w1.w,
                          w2.x, w2.y, w2.z, w2.w, w3.x, w3.y, w3.z, w3.w};
#pragma unroll
    for (int p = 0; p < PX; ++p)
#pragma unroll
      for (int d = 0; d < kKD; ++d)
        acc[p][d] = fmaf(fa[p], sw[p + d], acc[p][d]);
  };

#define WAITBAR(N)                                          \
  do {                                                      \
    asm volatile("s_waitcnt vmcnt(" #N ")" ::: "memory");   \
    __builtin_amdgcn_s_barrier();                           \
  } while (0)

  // ---- prologue: stage 3 channels, one full drain ----
  stage(0);                        // channel 0
  stage(1);                        // channel 1
  stage(2);                        // channel 2
  __syncthreads();                 // drains all; zpad + buf0/1/2 valid

  // ---- period-3 pipelined loop: 42 iters x 3 channels = 126 ----
  // Invariant at iter entry (c): outstanding = stage(b1->c+1), stage(b2->c+2).
  // Each vmcnt(4) retires the stage issued two phases earlier.
  for (int it = 0; it < 42; ++it) {
    compute(0);                    // channel c   (b0 valid)
    WAITBAR(4);                    // drain stage(b1->c+1); all waves off b0
    stage(0);                      // -> channel c+3
    compute(1);                    // channel c+1 (b1 valid)
    WAITBAR(4);                    // drain stage(b2->c+2); all waves off b1
    stage(1);                      // -> channel c+4
    compute(2);                    // channel c+2 (b2 valid)
    WAITBAR(4);                    // drain stage(b0->c+3); all waves off b2
    if (it != 41) stage(2);        // -> channel c+5 (skip: would be 128)
  }
  // here: b0 holds channel 126 (drained), b1 holds 127 (in flight)
  compute(0);                      // channel 126
  WAITBAR(0);                      // drain stage(b1->127)
  compute(1);                      // channel 127

#undef WAITBAR

  // epilogue: 9 dx channels x 8 px, coalesced dwordx4 stores (r2 verbatim)
  const float scale = 1.0f / (float)kC;
  float* obase = out + ((long long)b * 81 + (long long)dy * kKD) * kHW +
                 (long long)(y0 + yl) * kW + px0;
#pragma unroll
  for (int d = 0; d < kKD; ++d) {
    float4 o0 = make_float4(acc[0][d] * scale, acc[1][d] * scale,
                            acc[2][d] * scale, acc[3][d] * scale);
    float4 o1 = make_float4(acc[4][d] * scale, acc[5][d] * scale,
                            acc[6][d] * scale, acc[7][d] * scale);
    float* op = obase + (long long)d * kHW;
    *(float4*)op = o0;
    *(float4*)(op + 4) = o1;
  }
}

extern "C" void kernel_launch(void* const* d_in, const int* in_sizes, int n_in,
                              void* d_out, int out_size, void* d_ws, size_t ws_size,
                              hipStream_t stream) {
  const float* first = (const float*)d_in[0];
  const float* second = (const float*)d_in[1];
  float* out = (float*)d_out;

  const int grid = 8 * (kH / YT) * kKD;  // 8 * 14 * 9 = 1008 blocks
  corr81_kernel<<<grid, NT, 0, stream>>>(first, second, out);
}

// Round 8
// 322.357 us; speedup vs baseline: 1.8079x; 1.1735x over previous
//
#include <hip/hip_runtime.h>

// PWC-Net 9x9 correlation — r8: r2 body with F in registers (S-only LDS).
//
// History: r2 = 153us/dispatch (best), FETCH 86MB / WRITE 54MB clean.
// r7 (counted vmcnt graft) regressed to 250us -> r2's per-channel drain is
// already TLP-hidden; sync structure is NOT the bottleneck. r2's per-CU
// per-channel budget: LDS pipe ~1220cy (reads 567 + writes 370 + conflicts
// 283), L2 staging ~845cy, FMA 432cy -> LDS pipe dominates, and F is 1/3 of
// reads, 1/2 of writes, 1/3 of conflicts with ZERO cross-lane reuse.
// r8 = r2 verbatim except F never touches LDS: each lane loads its own 8
// pixels as two coalesced float4s per channel, double-buffered in named
// scalars (no arrays, no address-taken state — the r4/r6 scratch pathology
// correlated with restructured pointer walking, so the diff is kept ~10
// lines). S staging, window pointers, schedule, epilogue: r2 unchanged.
//
// OOB: second rows outside [0,H) -> staging source = zeroed __device__ row,
// stride 0. x-halo -> thread-constant pointer to 16B LDS zero pad.
// Numerics: identical fmaf chain and 1/C scale.

namespace {
constexpr int kC = 128;
constexpr int kH = 112;
constexpr int kW = 192;
constexpr int kD = 4;            // max displacement
constexpr int kKD = 9;           // 2*kD+1
constexpr int kHW = kH * kW;     // 21504
constexpr long long kCHW = (long long)kC * kHW;

constexpr int PX = 8;            // pixels per thread along x
constexpr int XG = kW / PX;      // 24 x-groups
constexpr int YT = 8;            // rows per block
constexpr int NT = XG * YT;      // 192 threads = 3 waves
constexpr int TILE = YT * kW;    // 1536 floats per staged channel tile
}  // namespace

// 768B of zeros: staging source for out-of-image second rows.
__device__ __attribute__((aligned(16))) float g_zero_row[kW] = {};

typedef const __attribute__((address_space(1))) void* gas_ptr;
typedef __attribute__((address_space(3))) void* las_ptr;

__device__ __forceinline__ void gload16(const float* g, float* l) {
  __builtin_amdgcn_global_load_lds((gas_ptr)g, (las_ptr)l, 16, 0, 0);
}

__global__ __launch_bounds__(NT, 4)
void corr81_kernel(const float* __restrict__ first,
                   const float* __restrict__ second,
                   float* __restrict__ out) {
  __shared__ __align__(16) float zpad[4];        // x-halo zeros
  __shared__ __align__(16) float Sb[2][TILE];    // second tiles (double buffer)

  const int g = blockIdx.x;
  const int b = g & 7;             // batch -> XCD slab
  const int i = g >> 3;
  const int dy = i % kKD;          // dy innermost -> L2 sliding window
  const int y0 = (i / kKD) * YT;

  const int tid = threadIdx.x;
  const int xg = tid % XG;
  const int yl = tid / XG;
  const int px0 = xg * PX;
  const int ys0 = y0 + dy - kD;    // first staged second-row (may be OOB)

  if (tid == 0) { zpad[0] = 0.f; zpad[1] = 0.f; zpad[2] = 0.f; zpad[3] = 0.f; }

  // ---- S staging source pointers (per lane, computed once; r2 verbatim) ----
  const float* ssrc[2];
  long long sstr[2];
#pragma unroll
  for (int j = 0; j < 2; ++j) {
    const int pos = j * NT + tid;          // 0..383
    const int r = pos / 48;                // staged row 0..7
    const int col4 = (pos - r * 48) * 4;   // float offset within row
    const int ysr = ys0 + r;
    const bool inb = (unsigned)ysr < (unsigned)kH;
    ssrc[j] = inb ? (second + (long long)b * kCHW + (long long)ysr * kW + col4)
                  : (g_zero_row + col4);
    sstr[j] = inb ? (long long)kHW : 0ll;
  }

  // ---- F source: lane's own 8 pixels, two coalesced float4s per channel.
  const float* fpg = first + (long long)b * kCHW +
                     (long long)(y0 + yl) * kW + px0;

  float acc[PX][kKD];
#pragma unroll
  for (int p = 0; p < PX; ++p)
#pragma unroll
    for (int d = 0; d < kKD; ++d) acc[p][d] = 0.0f;

  // issue 2 x global_load_lds (6KB S tile) into buffer P, advance
  auto stage = [&](int P) {
    gload16(ssrc[0], &Sb[P][tid * 4]);
    gload16(ssrc[1], &Sb[P][tid * 4 + NT * 4]);
    ssrc[0] += sstr[0];
    ssrc[1] += sstr[1];
  };

  // 4 x ds_read_b128 + 72 FMA from buffer P; F from register args
  auto compute = [&](int P, const float4 f0, const float4 f1) {
    const float* s1 = &Sb[P][yl * kW + px0];
    const float* w0p = (xg == 0) ? zpad : (s1 - 4);       // window [-4,0)
    const float* w3p = (xg == XG - 1) ? zpad : (s1 + 8);  // window [12,16)
    const float4 w0 = *(const float4*)(w0p);
    const float4 w1 = *(const float4*)(s1);
    const float4 w2 = *(const float4*)(s1 + 4);
    const float4 w3 = *(const float4*)(w3p);

    const float fa[PX] = {f0.x, f0.y, f0.z, f0.w, f1.x, f1.y, f1.z, f1.w};
    const float sw[16] = {w0.x, w0.y, w0.z, w0.w, w1.x, w1.y, w1.z, w1.w,
                          w2.x, w2.y, w2.z, w2.w, w3.x, w3.y, w3.z, w3.w};
#pragma unroll
    for (int p = 0; p < PX; ++p)
#pragma unroll
      for (int d = 0; d < kKD; ++d)
        acc[p][d] = fmaf(fa[p], sw[p + d], acc[p][d]);
  };

  // ---- software-pipelined channel loop (r2 schedule, unroll 2) ----
  float4 fa0, fa1, fb0, fb1;
  stage(0);                              // S for c = 0
  fa0 = *(const float4*)(fpg);           // F for c = 0
  fa1 = *(const float4*)(fpg + 4);
  fpg += kHW;
  __syncthreads();                       // buf0 + zpad ready
  for (int c = 0; c < kC; c += 2) {
    stage(1);                            // S for c+1
    fb0 = *(const float4*)(fpg);         // F for c+1
    fb1 = *(const float4*)(fpg + 4);
    fpg += kHW;
    compute(0, fa0, fa1);                // channel c
    __syncthreads();                     // buf1 ready; buf0 consumed
    if (c + 2 < kC) {
      stage(0);                          // S for c+2
      fa0 = *(const float4*)(fpg);       // F for c+2
      fa1 = *(const float4*)(fpg + 4);
      fpg += kHW;
    }
    compute(1, fb0, fb1);                // channel c+1
    __syncthreads();                     // buf0 ready; buf1 consumed
  }

  // epilogue: 9 dx channels x 8 px, coalesced dwordx4 stores (r2 verbatim)
  const float scale = 1.0f / (float)kC;
  float* obase = out + ((long long)b * 81 + (long long)dy * kKD) * kHW +
                 (long long)(y0 + yl) * kW + px0;
#pragma unroll
  for (int d = 0; d < kKD; ++d) {
    float4 o0 = make_float4(acc[0][d] * scale, acc[1][d] * scale,
                            acc[2][d] * scale, acc[3][d] * scale);
    float4 o1 = make_float4(acc[4][d] * scale, acc[5][d] * scale,
                            acc[6][d] * scale, acc[7][d] * scale);
    float* op = obase + (long long)d * kHW;
    *(float4*)op = o0;
    *(float4*)(op + 4) = o1;
  }
}

extern "C" void kernel_launch(void* const* d_in, const int* in_sizes, int n_in,
                              void* d_out, int out_size, void* d_ws, size_t ws_size,
                              hipStream_t stream) {
  const float* first = (const float*)d_in[0];
  const float* second = (const float*)d_in[1];
  float* out = (float*)d_out;

  const int grid = 8 * (kH / YT) * kKD;  // 8 * 14 * 9 = 1008 blocks
  corr81_kernel<<<grid, NT, 0, stream>>>(first, second, out);
}

// Round 9
// 301.196 us; speedup vs baseline: 1.9349x; 1.0703x over previous
//
#include <hip/hip_runtime.h>

// PWC-Net 9x9 correlation — r9: dy-merge x3, halo-padded S tile, PX=4.
//
// Evidence so far: r2 (153us) wins because ALL global traffic is
// lane-contiguous global_load_lds; r0/r8 (203-205us) lose via strided
// global->VGPR loads; r7 (sync graft) and r4/r5/r6 (body rewrites) regress.
// None of the pipes is saturated in r2 -> attack traffic VOLUME: the dy=9
// grid re-stages each S/F tile ~9x. This kernel merges 3 consecutive dy
// per block:
//   PX=4 -> every lane's 16B is contiguous: F is a single coalesced float4
//   register load per channel (clean now, unlike r8's 32B-stride), S reads
//   are lane-contiguous b128.
//   S tile = [6 rows][200 floats] halo-padded: staged as a 16B-slot
//   permutation (50 slots/row; slot k holds cols [4k-4,4k), k==0/49 and
//   OOB rows sourced from a zeroed __device__ row) -> global_load_lds dest
//   stays linear, and compute has NO halo branches: window [px0-4,px0+8)
//   = 3 b128 reads at immediate offsets.
//   acc[4][27] constant-indexed (proven shape); launch_bounds(192,3) so
//   ~150 live regs don't spill.
// Traffic per block-channel: S 4.8KB + F 3KB for 3 dy x 4 rows of output
// (vs r2: 12KB for 1 dy x 8 rows) -> ~3x less L2->CU per useful output.
// Schedule = r2 verbatim (double buffer, one __syncthreads per channel).
//
// Numerics: channel-sequential fmaf chain, 1/C scale (matches baseline).

namespace {
constexpr int kC = 128;
constexpr int kH = 112;
constexpr int kW = 192;
constexpr int kD = 4;             // max displacement
constexpr int kKD = 9;            // 2*kD+1
constexpr int kHW = kH * kW;      // 21504
constexpr long long kCHW = (long long)kC * kHW;

constexpr int PX = 4;             // pixels per thread along x
constexpr int XG = kW / PX;       // 48 lanes cover one row (16B each)
constexpr int YT = 4;             // output rows per block
constexpr int NT = XG * YT;       // 192 threads = 3 waves
constexpr int DYM = 3;            // dy values merged per block
constexpr int NACC = DYM * kKD;   // 27 accumulators per pixel

constexpr int SROWF = 200;        // padded S row: 4 + 192 + 4 floats
constexpr int SROWS = YT + 2;     // 6 S rows cover yl in [0,4) x j in [0,3)
constexpr int SSLOT = SROWS * 50; // 300 16B slots per S tile
constexpr int STILEF = SROWS * SROWF;  // 1200 floats
}  // namespace

// 768B of zeros: staging source for pad slots and out-of-image rows.
__device__ __attribute__((aligned(16))) float g_zero_row[kW] = {};

typedef const __attribute__((address_space(1))) void* gas_ptr;
typedef __attribute__((address_space(3))) void* las_ptr;

__device__ __forceinline__ void gload16(const float* g, float* l) {
  __builtin_amdgcn_global_load_lds((gas_ptr)g, (las_ptr)l, 16, 0, 0);
}

__global__ __launch_bounds__(NT, 3)
void corr81_kernel(const float* __restrict__ first,
                   const float* __restrict__ second,
                   float* __restrict__ out) {
  __shared__ __align__(16) float Sb[2][STILEF];   // 2 x 4.8KB

  const int g = blockIdx.x;
  const int b = g & 7;              // batch -> XCD slab
  const int i = g >> 3;
  const int dyb = (i % DYM) * DYM;  // dy base: 0,3,6 (innermost -> L2 slide)
  const int y0 = (i / DYM) * YT;

  const int tid = threadIdx.x;
  const int xg = tid % XG;
  const int yl = tid / XG;          // 0..3
  const int px0 = xg * PX;

  // ---- S staging sources: slots tid and tid+NT (latter only tid<108).
  // slot s -> padded row r = s/50, slot-in-row k = s%50. Slot k holds
  // global cols [4k-4, 4k) of S row (y0+dyb-4+r); k==0, k==49, or OOB row
  // -> zeroed source, stride 0.
  const float* ssrc[2];
  long long sstr[2];
#pragma unroll
  for (int j = 0; j < 2; ++j) {
    const int slot = j * NT + tid;         // 0..383 (>=SSLOT unused)
    const int r = slot / 50;
    const int k = slot % 50;
    const int ys = y0 + dyb - kD + r;
    const bool ok = (k >= 1) && (k <= 48) && ((unsigned)ys < (unsigned)kH) &&
                    (slot < SSLOT);
    ssrc[j] = ok ? (second + (long long)b * kCHW + (long long)ys * kW +
                    (4 * k - 4))
                 : g_zero_row;
    sstr[j] = ok ? (long long)kHW : 0ll;
  }

  // ---- F source: lane's own 4 pixels; 16B lane stride -> fully coalesced.
  const float* fpg = first + (long long)b * kCHW +
                     (long long)(y0 + yl) * kW + px0;

  float acc[PX][NACC];
#pragma unroll
  for (int p = 0; p < PX; ++p)
#pragma unroll
    for (int a = 0; a < NACC; ++a) acc[p][a] = 0.0f;

  // stage one channel's padded S tile (300 slots) into buffer P
  auto stage = [&](int P) {
    gload16(ssrc[0], &Sb[P][tid * 4]);
    if (tid < SSLOT - NT) gload16(ssrc[1], &Sb[P][(tid + NT) * 4]);
    ssrc[0] += sstr[0];
    ssrc[1] += sstr[1];
  };

  // one channel: 9 lane-contiguous ds_read_b128 + 108 FMA; F in register.
  // Padded col of global col x is x+4, so window [px0-4, px0+8) starts at
  // padded float offset (yl+j)*SROWF + px0.
  auto compute = [&](int P, const float4 f) {
    const float* s = &Sb[P][yl * SROWF + px0];
    const float fv[PX] = {f.x, f.y, f.z, f.w};
#pragma unroll
    for (int j = 0; j < DYM; ++j) {
      const float4 w0 = *(const float4*)(s + j * SROWF);
      const float4 w1 = *(const float4*)(s + j * SROWF + 4);
      const float4 w2 = *(const float4*)(s + j * SROWF + 8);
      const float sw[12] = {w0.x, w0.y, w0.z, w0.w, w1.x, w1.y, w1.z, w1.w,
                            w2.x, w2.y, w2.z, w2.w};
#pragma unroll
      for (int p = 0; p < PX; ++p)
#pragma unroll
        for (int d = 0; d < kKD; ++d)
          acc[p][j * kKD + d] = fmaf(fv[p], sw[p + d], acc[p][j * kKD + d]);
    }
  };

  // ---- software-pipelined channel loop (r2 schedule, unroll 2) ----
  float4 fa, fb;
  stage(0);                              // S for c = 0
  fa = *(const float4*)fpg; fpg += kHW;  // F for c = 0
  __syncthreads();                       // buf0 ready
  for (int c = 0; c < kC; c += 2) {
    stage(1);                            // S for c+1
    fb = *(const float4*)fpg; fpg += kHW;
    compute(0, fa);                      // channel c
    __syncthreads();                     // buf1 ready; buf0 consumed
    if (c + 2 < kC) {
      stage(0);                          // S for c+2
      fa = *(const float4*)fpg; fpg += kHW;
    }
    compute(1, fb);                      // channel c+1
    __syncthreads();                     // buf0 ready; buf1 consumed
  }

  // epilogue: 27 output channels x 4 px, coalesced dwordx4 stores
  const float scale = 1.0f / (float)kC;
  float* obase = out + (long long)b * 81 * kHW +
                 (long long)(y0 + yl) * kW + px0;
#pragma unroll
  for (int j = 0; j < DYM; ++j)
#pragma unroll
    for (int d = 0; d < kKD; ++d) {
      float4 o = make_float4(acc[0][j * kKD + d] * scale,
                             acc[1][j * kKD + d] * scale,
                             acc[2][j * kKD + d] * scale,
                             acc[3][j * kKD + d] * scale);
      *(float4*)(obase + (long long)((dyb + j) * kKD + d) * kHW) = o;
    }
}

extern "C" void kernel_launch(void* const* d_in, const int* in_sizes, int n_in,
                              void* d_out, int out_size, void* d_ws, size_t ws_size,
                              hipStream_t stream) {
  const float* first = (const float*)d_in[0];
  const float* second = (const float*)d_in[1];
  float* out = (float*)d_out;

  const int grid = 8 * (kH / YT) * DYM;  // 8 * 28 * 3 = 672 blocks
  corr81_kernel<<<grid, NT, 0, stream>>>(first, second, out);
}

// Round 10
// 292.500 us; speedup vs baseline: 1.9925x; 1.0297x over previous
//
#include <hip/hip_runtime.h>

// PWC-Net 9x9 correlation — r10: x-split for 2x TLP (7.9 blocks/CU).
//
// Ladder: r2 = 153us (best). r9 cut L2->CU traffic 3x -> SLOWER (172us,
// 2.6 blocks/CU): traffic volume refuted. All clean variants sit at
// ~3000 cyc/channel wall vs ~430 cyc FMA issue with no pipe >23% busy ->
// the per-channel stage->drain->read->FMA chain is latency-bound and only
// co-resident blocks at different phases hide it (r7 proved sync grafts
// can't). So: double blocks/CU. Each block now covers 96 px (half row),
// YT=8, NT=192 (3 waves, r2 barrier width), grid 8*14*2*9 = 2016.
//  - S tile [8][104] halo-padded, staged as 16B-slot permutation
//    (r9-proven): pad/OOB slots sourced from zero row, LDS dest linear,
//    compute = 3 immediate-offset b128 reads, NO halo branches.
//  - F: lane's own contiguous 16B -> coalesced float4 register load
//    (r9-proven at PX=4), double-buffered in named scalars.
//  - acc[4][9]=36 VGPR, LDS 6.7KB -> occupancy ~24 waves/CU possible.
// Schedule, OOB, numerics: r2 verbatim (1/C scale, channel-seq fmaf).

namespace {
constexpr int kC = 128;
constexpr int kH = 112;
constexpr int kW = 192;
constexpr int kD = 4;             // max displacement
constexpr int kKD = 9;            // 2*kD+1
constexpr int kHW = kH * kW;      // 21504
constexpr long long kCHW = (long long)kC * kHW;

constexpr int PX = 4;             // pixels per thread along x
constexpr int XB = 96;            // x-extent per block
constexpr int XG = XB / PX;       // 24 lanes per row
constexpr int YT = 8;             // rows per block
constexpr int NT = XG * YT;       // 192 threads = 3 waves
constexpr int NXT = kW / XB;      // 2 x-tiles

constexpr int SROWF = XB + 8;     // padded S row: 4 + 96 + 4 floats
constexpr int SLOTR = SROWF / 4;  // 26 slots per row
constexpr int SSLOT = YT * SLOTR; // 208 slots per tile
constexpr int STILEF = YT * SROWF;  // 832 floats = 3.25KB
}  // namespace

// zeros: staging source for pad slots and out-of-image rows.
__device__ __attribute__((aligned(16))) float g_zero_row[kW] = {};

typedef const __attribute__((address_space(1))) void* gas_ptr;
typedef __attribute__((address_space(3))) void* las_ptr;

__device__ __forceinline__ void gload16(const float* g, float* l) {
  __builtin_amdgcn_global_load_lds((gas_ptr)g, (las_ptr)l, 16, 0, 0);
}

__global__ __launch_bounds__(NT, 6)
void corr81_kernel(const float* __restrict__ first,
                   const float* __restrict__ second,
                   float* __restrict__ out) {
  __shared__ __align__(16) float Sb[2][STILEF];   // 2 x 3.25KB

  const int g = blockIdx.x;
  const int b = g & 7;              // batch -> XCD slab
  const int i = g >> 3;
  const int dy = i % kKD;           // dy innermost -> L2 sliding window
  const int xt = (i / kKD) % NXT;   // x-tile
  const int y0 = (i / (kKD * NXT)) * YT;
  const int x0 = xt * XB;

  const int tid = threadIdx.x;
  const int xg = tid % XG;          // 0..23
  const int yl = tid / XG;          // 0..7
  const int px = x0 + xg * PX;      // lane's first output pixel

  // ---- S staging sources: slots tid and tid+NT (latter only tid<16).
  // slot s -> row r = s/26, slot-in-row k = s%26; holds global cols
  // [x0-4+4k, x0+4k) of S row (y0+dy-4+r). Pad/OOB -> zero row, stride 0.
  const float* ssrc[2];
  long long sstr[2];
#pragma unroll
  for (int j = 0; j < 2; ++j) {
    const int s = j * NT + tid;
    const int r = s / SLOTR;
    const int k = s % SLOTR;
    const int gc = x0 - 4 + 4 * k;         // global col base of this slot
    const int ys = y0 + dy - kD + r;
    const bool ok = (s < SSLOT) && (gc >= 0) && (gc <= kW - 4) &&
                    ((unsigned)ys < (unsigned)kH);
    ssrc[j] = ok ? (second + (long long)b * kCHW + (long long)ys * kW + gc)
                 : g_zero_row;
    sstr[j] = ok ? (long long)kHW : 0ll;
  }

  // ---- F source: lane's own 4 pixels, contiguous 16B -> coalesced.
  const float* fpg = first + (long long)b * kCHW +
                     (long long)(y0 + yl) * kW + px;

  float acc[PX][kKD];
#pragma unroll
  for (int p = 0; p < PX; ++p)
#pragma unroll
    for (int d = 0; d < kKD; ++d) acc[p][d] = 0.0f;

  // stage one channel's padded S tile (208 slots) into buffer P
  auto stage = [&](int P) {
    gload16(ssrc[0], &Sb[P][tid * 4]);
    if (tid < SSLOT - NT) gload16(ssrc[1], &Sb[P][(tid + NT) * 4]);
    ssrc[0] += sstr[0];
    ssrc[1] += sstr[1];
  };

  // one channel: 3 lane-contiguous b128 reads (immediate offsets) + 36 FMA.
  // Padded offset of global col x is x - x0 + 4, so window [px-4, px+8)
  // starts at padded float offset yl*SROWF + xg*4.
  auto compute = [&](int P, const float4 f) {
    const float* s = &Sb[P][yl * SROWF + xg * PX];
    const float4 w0 = *(const float4*)(s);
    const float4 w1 = *(const float4*)(s + 4);
    const float4 w2 = *(const float4*)(s + 8);
    const float sw[12] = {w0.x, w0.y, w0.z, w0.w, w1.x, w1.y, w1.z, w1.w,
                          w2.x, w2.y, w2.z, w2.w};
    const float fv[PX] = {f.x, f.y, f.z, f.w};
#pragma unroll
    for (int p = 0; p < PX; ++p)
#pragma unroll
      for (int d = 0; d < kKD; ++d)
        acc[p][d] = fmaf(fv[p], sw[p + d], acc[p][d]);
  };

  // ---- software-pipelined channel loop (r2 schedule, unroll 2) ----
  float4 fa, fb;
  stage(0);                              // S for c = 0
  fa = *(const float4*)fpg; fpg += kHW;  // F for c = 0
  __syncthreads();                       // buf0 ready
  for (int c = 0; c < kC; c += 2) {
    stage(1);                            // S for c+1
    fb = *(const float4*)fpg; fpg += kHW;
    compute(0, fa);                      // channel c
    __syncthreads();                     // buf1 ready; buf0 consumed
    if (c + 2 < kC) {
      stage(0);                          // S for c+2
      fa = *(const float4*)fpg; fpg += kHW;
    }
    compute(1, fb);                      // channel c+1
    __syncthreads();                     // buf0 ready; buf1 consumed
  }

  // epilogue: 9 dx channels x 4 px, coalesced dwordx4 stores
  const float scale = 1.0f / (float)kC;
  float* obase = out + ((long long)b * 81 + (long long)dy * kKD) * kHW +
                 (long long)(y0 + yl) * kW + px;
#pragma unroll
  for (int d = 0; d < kKD; ++d) {
    float4 o = make_float4(acc[0][d] * scale, acc[1][d] * scale,
                           acc[2][d] * scale, acc[3][d] * scale);
    *(float4*)(obase + (long long)d * kHW) = o;
  }
}

extern "C" void kernel_launch(void* const* d_in, const int* in_sizes, int n_in,
                              void* d_out, int out_size, void* d_ws, size_t ws_size,
                              hipStream_t stream) {
  const float* first = (const float*)d_in[0];
  const float* second = (const float*)d_in[1];
  float* out = (float*)d_out;

  const int grid = 8 * (kH / YT) * NXT * kKD;  // 8 * 14 * 2 * 9 = 2016
  corr81_kernel<<<grid, NT, 0, stream>>>(first, second, out);
}